// Round 1
// baseline (2333.497 us; speedup 1.0000x reference)
//
#include <hip/hip_runtime.h>
#include <stdint.h>

// Problem constants
#define TTOK 4096
#define DMODEL 512
#define NHEAD 8
#define FFDIM 2048
#define NLAYER 6

typedef short bf16x8 __attribute__((ext_vector_type(8)));
typedef float f32x4 __attribute__((ext_vector_type(4)));

__device__ __forceinline__ unsigned short f2bf(float f) {
  union { float f; unsigned int u; } v; v.f = f;
  unsigned int u = v.u;
  unsigned int r = (u + 0x7FFFu + ((u >> 16) & 1u)) >> 16;
  return (unsigned short)r;
}

// ---------------------------------------------------------------------------
// Weight prep: transpose + cast f32 [K][N] -> bf16 [N][K]
// ---------------------------------------------------------------------------
__global__ void transpose_cast(const float* __restrict__ src, unsigned short* __restrict__ dst,
                               int K, int N) {
  __shared__ float tile[32][33];
  const int n0 = blockIdx.x * 32, k0 = blockIdx.y * 32;
  const int x = threadIdx.x, y = threadIdx.y;
#pragma unroll
  for (int yy = 0; yy < 32; yy += 8)
    tile[y + yy][x] = src[(size_t)(k0 + y + yy) * N + n0 + x];
  __syncthreads();
#pragma unroll
  for (int yy = 0; yy < 32; yy += 8)
    dst[(size_t)(n0 + y + yy) * K + k0 + x] = f2bf(tile[x][y + yy]);
}

__global__ void pack_bias(const float* __restrict__ bq, const float* __restrict__ bk,
                          const float* __restrict__ bv, const float* __restrict__ bc,
                          float* __restrict__ out) {
  int i = blockIdx.x * 256 + threadIdx.x;
  const float* src = (i < 512) ? bq : (i < 1024) ? bk : (i < 1536) ? bv : bc;
  out[i] = src[i & 511];
}

__global__ void cast_bf16(const float* __restrict__ src, unsigned short* __restrict__ dst, int n4) {
  int i = blockIdx.x * 256 + threadIdx.x;
  if (i < n4) {
    float4 v = ((const float4*)src)[i];
    uint2 o;
    o.x = (unsigned int)f2bf(v.x) | ((unsigned int)f2bf(v.y) << 16);
    o.y = (unsigned int)f2bf(v.z) | ((unsigned int)f2bf(v.w) << 16);
    ((uint2*)dst)[i] = o;
  }
}

__global__ void seg_bounds(const int* __restrict__ seg, int* __restrict__ ss,
                           int* __restrict__ se, int T) {
  const int t = blockIdx.x * 256 + threadIdx.x;
  if (t >= T) return;
  const int sid = seg[t];
  int lo = 0, hi = T;
  while (lo < hi) { int mid = (lo + hi) >> 1; if (seg[mid] < sid) lo = mid + 1; else hi = mid; }
  ss[t] = lo;
  lo = t; hi = T;
  while (lo < hi) { int mid = (lo + hi) >> 1; if (seg[mid] <= sid) lo = mid + 1; else hi = mid; }
  se[t] = lo;
}

// ---------------------------------------------------------------------------
// bf16 MFMA GEMM: C[M,N] = A[M,K] * Bt[N,K]^T  (+bias, optional res/swish)
// MODE 0: out_bf16 = acc + bias
// MODE 1: out_f32  = res + acc + bias
// MODE 2: out_bf16 = swish(acc + bias)
// 128x128 tile, BK=64, 256 threads (4 waves, 2x2 of 64x64), 16x16x32 MFMA.
// LDS row-major with 16B-unit XOR swizzle: unit' = unit ^ (row&7).
// ---------------------------------------------------------------------------
template <int MODE>
__launch_bounds__(256)
__global__ void gemm_bf16(const unsigned short* __restrict__ A,
                          const unsigned short* __restrict__ Bt,
                          int M, int N, int K,
                          const float* __restrict__ bias,
                          const float* __restrict__ res,
                          float* __restrict__ outF,
                          unsigned short* __restrict__ outB) {
  __shared__ uint4 As[1024];  // 128 rows x 8 x 16B = 16KB
  __shared__ uint4 Bs[1024];
  const int tid = threadIdx.x;
  const int lane = tid & 63;
  const int wv = tid >> 6;
  const int wm = wv >> 1, wn = wv & 1;
  const int l15 = lane & 15, l4 = lane >> 4;
  const int bm0 = blockIdx.x * 128;
  const int bn0 = blockIdx.y * 128;

  f32x4 acc[4][4];
#pragma unroll
  for (int m = 0; m < 4; ++m)
#pragma unroll
    for (int n = 0; n < 4; ++n) acc[m][n] = (f32x4){0.f, 0.f, 0.f, 0.f};

  for (int k0 = 0; k0 < K; k0 += 64) {
#pragma unroll
    for (int i = 0; i < 4; ++i) {
      const int d = tid + i * 256;
      const int r = d >> 3, c = d & 7;
      const uint4 va = *((const uint4*)(A + (size_t)(bm0 + r) * K + k0) + c);
      const uint4 vb = *((const uint4*)(Bt + (size_t)(bn0 + r) * K + k0) + c);
      const int u = r * 8 + (c ^ (r & 7));
      As[u] = va;
      Bs[u] = vb;
    }
    __syncthreads();
#pragma unroll
    for (int kk = 0; kk < 2; ++kk) {
      bf16x8 af[4], bfr[4];
#pragma unroll
      for (int m = 0; m < 4; ++m) {
        const int row = wm * 64 + m * 16 + l15;
        const int c = kk * 4 + l4;
        af[m] = *(const bf16x8*)&As[row * 8 + (c ^ (row & 7))];
      }
#pragma unroll
      for (int n = 0; n < 4; ++n) {
        const int row = wn * 64 + n * 16 + l15;
        const int c = kk * 4 + l4;
        bfr[n] = *(const bf16x8*)&Bs[row * 8 + (c ^ (row & 7))];
      }
#pragma unroll
      for (int m = 0; m < 4; ++m)
#pragma unroll
        for (int n = 0; n < 4; ++n)
          acc[m][n] = __builtin_amdgcn_mfma_f32_16x16x32_bf16(af[m], bfr[n], acc[m][n], 0, 0, 0);
    }
    __syncthreads();
  }

  float bvals[4];
#pragma unroll
  for (int n = 0; n < 4; ++n) bvals[n] = bias[bn0 + wn * 64 + n * 16 + l15];

#pragma unroll
  for (int m = 0; m < 4; ++m) {
#pragma unroll
    for (int r = 0; r < 4; ++r) {
      const int R = bm0 + wm * 64 + m * 16 + l4 * 4 + r;
#pragma unroll
      for (int n = 0; n < 4; ++n) {
        const int C = bn0 + wn * 64 + n * 16 + l15;
        float v = acc[m][n][r] + bvals[n];
        if (MODE == 1) {
          v += res[(size_t)R * N + C];
          outF[(size_t)R * N + C] = v;
        } else if (MODE == 2) {
          v = v / (1.f + __expf(-v));
          outB[(size_t)R * N + C] = f2bf(v);
        } else {
          outB[(size_t)R * N + C] = f2bf(v);
        }
      }
    }
  }
}

// ---------------------------------------------------------------------------
// Segment-local attention, fp32, flash-style.
// qkvcb: [T][2048] bf16 (q|k|v|c sections of 512 each, head-major inside).
// Block: 256 threads = 64 q-rows x 4 parts (16 dims each), one head.
// Grid: (T/64, H). Output: aob[T][512] bf16 = att@v + c.
// ---------------------------------------------------------------------------
__launch_bounds__(256)
__global__ void attn_kernel(const unsigned short* __restrict__ qkvcb,
                            const int* __restrict__ sstart,
                            const int* __restrict__ send,
                            unsigned short* __restrict__ aob) {
  __shared__ float Ks[64][64];
  __shared__ float Vs[64][64];
  const int tid = threadIdx.x;
  const int rl = tid >> 2;
  const int part = tid & 3;
  const int row = blockIdx.x * 64 + rl;
  const int head = blockIdx.y;
  const int qo = head * 64 + part * 16;

  float q[16];
  {
    const uint4* qp = (const uint4*)(qkvcb + (size_t)row * 2048 + qo);
    uint4 u0 = qp[0], u1 = qp[1];
    unsigned int uu[8] = {u0.x, u0.y, u0.z, u0.w, u1.x, u1.y, u1.z, u1.w};
#pragma unroll
    for (int i = 0; i < 8; ++i) {
      union { unsigned int u; float f; } a, b;
      a.u = uu[i] << 16; b.u = uu[i] & 0xFFFF0000u;
      q[2 * i] = a.f; q[2 * i + 1] = b.f;
    }
  }
  const int s = sstart[row], e = send[row];
  const int s0 = sstart[blockIdx.x * 64];
  const int e1 = send[blockIdx.x * 64 + 63];
  float mx = -INFINITY, lsum = 0.f;
  float acc[16];
#pragma unroll
  for (int i = 0; i < 16; ++i) acc[i] = 0.f;

  for (int k0 = s0; k0 < e1; k0 += 64) {
    // stage K,V tiles (bf16 -> f32)
#pragma unroll
    for (int i = 0; i < 4; ++i) {
      const int ch = tid + i * 256;
      const int mat = ch >> 9;          // 0=K, 1=V
      const int j = (ch >> 3) & 63;
      const int d8 = ch & 7;
      if (k0 + j < e1) {
        const uint4 u = *(const uint4*)(qkvcb + (size_t)(k0 + j) * 2048 + 512 + mat * 512 + head * 64 + d8 * 8);
        float* dr = (mat ? Vs[j] : Ks[j]) + d8 * 8;
        unsigned int uu[4] = {u.x, u.y, u.z, u.w};
#pragma unroll
        for (int t2 = 0; t2 < 4; ++t2) {
          union { unsigned int u; float f; } a, b;
          a.u = uu[t2] << 16; b.u = uu[t2] & 0xFFFF0000u;
          dr[2 * t2] = a.f; dr[2 * t2 + 1] = b.f;
        }
      }
    }
    __syncthreads();
    const int jlo = max(s - k0, 0), jhi = min(e - k0, 64);
    for (int j = jlo; j < jhi; ++j) {
      const float4* kr = (const float4*)&Ks[j][part * 16];
      float4 ka = kr[0], kb = kr[1], kc = kr[2], kd = kr[3];
      float d0 = q[0] * ka.x + q[4] * kb.x + q[8] * kc.x + q[12] * kd.x;
      float d1 = q[1] * ka.y + q[5] * kb.y + q[9] * kc.y + q[13] * kd.y;
      float d2 = q[2] * ka.z + q[6] * kb.z + q[10] * kc.z + q[14] * kd.z;
      float d3 = q[3] * ka.w + q[7] * kb.w + q[11] * kc.w + q[15] * kd.w;
      float sc = (d0 + d1) + (d2 + d3);
      sc += __shfl_xor(sc, 1);
      sc += __shfl_xor(sc, 2);
      sc *= 0.125f;  // 1/sqrt(64)
      const float4* vr = (const float4*)&Vs[j][part * 16];
      float4 va = vr[0], vb = vr[1], vc = vr[2], vd = vr[3];
      if (sc <= mx) {
        const float p = __expf(sc - mx);
        lsum += p;
        acc[0] += p * va.x; acc[1] += p * va.y; acc[2] += p * va.z; acc[3] += p * va.w;
        acc[4] += p * vb.x; acc[5] += p * vb.y; acc[6] += p * vb.z; acc[7] += p * vb.w;
        acc[8] += p * vc.x; acc[9] += p * vc.y; acc[10] += p * vc.z; acc[11] += p * vc.w;
        acc[12] += p * vd.x; acc[13] += p * vd.y; acc[14] += p * vd.z; acc[15] += p * vd.w;
      } else {
        const float corr = __expf(mx - sc);
        mx = sc;
        lsum = lsum * corr + 1.f;
        acc[0] = acc[0] * corr + va.x; acc[1] = acc[1] * corr + va.y;
        acc[2] = acc[2] * corr + va.z; acc[3] = acc[3] * corr + va.w;
        acc[4] = acc[4] * corr + vb.x; acc[5] = acc[5] * corr + vb.y;
        acc[6] = acc[6] * corr + vb.z; acc[7] = acc[7] * corr + vb.w;
        acc[8] = acc[8] * corr + vc.x; acc[9] = acc[9] * corr + vc.y;
        acc[10] = acc[10] * corr + vc.z; acc[11] = acc[11] * corr + vc.w;
        acc[12] = acc[12] * corr + vd.x; acc[13] = acc[13] * corr + vd.y;
        acc[14] = acc[14] * corr + vd.z; acc[15] = acc[15] * corr + vd.w;
      }
    }
    __syncthreads();
  }
  const float rinv = 1.f / lsum;
  const uint4* cp = (const uint4*)(qkvcb + (size_t)row * 2048 + 1536 + qo);
  uint4 c0 = cp[0], c1 = cp[1];
  unsigned int cc[8] = {c0.x, c0.y, c0.z, c0.w, c1.x, c1.y, c1.z, c1.w};
  unsigned short ov[16];
#pragma unroll
  for (int i = 0; i < 8; ++i) {
    union { unsigned int u; float f; } a, b;
    a.u = cc[i] << 16; b.u = cc[i] & 0xFFFF0000u;
    ov[2 * i] = f2bf(acc[2 * i] * rinv + a.f);
    ov[2 * i + 1] = f2bf(acc[2 * i + 1] * rinv + b.f);
  }
  uint4 o0, o1;
  o0.x = (unsigned int)ov[0] | ((unsigned int)ov[1] << 16);
  o0.y = (unsigned int)ov[2] | ((unsigned int)ov[3] << 16);
  o0.z = (unsigned int)ov[4] | ((unsigned int)ov[5] << 16);
  o0.w = (unsigned int)ov[6] | ((unsigned int)ov[7] << 16);
  o1.x = (unsigned int)ov[8] | ((unsigned int)ov[9] << 16);
  o1.y = (unsigned int)ov[10] | ((unsigned int)ov[11] << 16);
  o1.z = (unsigned int)ov[12] | ((unsigned int)ov[13] << 16);
  o1.w = (unsigned int)ov[14] | ((unsigned int)ov[15] << 16);
  uint4* op = (uint4*)(aob + (size_t)row * 512 + qo);
  op[0] = o0; op[1] = o1;
}

// ---------------------------------------------------------------------------
// TF-style LayerNorm over D=512: out = g*(x-u)/sqrt(var+1e-12)+b
// One wave per row; writes f32 (residual source / final out) + bf16 (GEMM A).
// ---------------------------------------------------------------------------
__launch_bounds__(64)
__global__ void ln_kernel(const float* __restrict__ x, const float* __restrict__ g,
                          const float* __restrict__ b, float* __restrict__ outF,
                          unsigned short* __restrict__ outB) {
  const int row = blockIdx.x;
  const int lane = threadIdx.x;
  const float4* xr = (const float4*)(x + (size_t)row * 512);
  float4 a = xr[lane * 2], c = xr[lane * 2 + 1];
  float s = a.x + a.y + a.z + a.w + c.x + c.y + c.z + c.w;
  float sq = a.x * a.x + a.y * a.y + a.z * a.z + a.w * a.w +
             c.x * c.x + c.y * c.y + c.z * c.z + c.w * c.w;
#pragma unroll
  for (int off = 1; off < 64; off <<= 1) {
    s += __shfl_xor(s, off);
    sq += __shfl_xor(sq, off);
  }
  const float mean = s * (1.f / 512.f);
  const float var = sq * (1.f / 512.f) - mean * mean;
  const float rstd = rsqrtf(var + 1e-12f);
  const float4* gr = (const float4*)g;
  const float4* br = (const float4*)b;
  float4 g0 = gr[lane * 2], g1v = gr[lane * 2 + 1];
  float4 b0 = br[lane * 2], b1v = br[lane * 2 + 1];
  float4 y0, y1;
  y0.x = (a.x - mean) * rstd * g0.x + b0.x;
  y0.y = (a.y - mean) * rstd * g0.y + b0.y;
  y0.z = (a.z - mean) * rstd * g0.z + b0.z;
  y0.w = (a.w - mean) * rstd * g0.w + b0.w;
  y1.x = (c.x - mean) * rstd * g1v.x + b1v.x;
  y1.y = (c.y - mean) * rstd * g1v.y + b1v.y;
  y1.z = (c.z - mean) * rstd * g1v.z + b1v.z;
  y1.w = (c.w - mean) * rstd * g1v.w + b1v.w;
  float4* of = (float4*)(outF + (size_t)row * 512);
  of[lane * 2] = y0;
  of[lane * 2 + 1] = y1;
  uint4 ob;
  ob.x = (unsigned int)f2bf(y0.x) | ((unsigned int)f2bf(y0.y) << 16);
  ob.y = (unsigned int)f2bf(y0.z) | ((unsigned int)f2bf(y0.w) << 16);
  ob.z = (unsigned int)f2bf(y1.x) | ((unsigned int)f2bf(y1.y) << 16);
  ob.w = (unsigned int)f2bf(y1.z) | ((unsigned int)f2bf(y1.w) << 16);
  ((uint4*)(outB + (size_t)row * 512))[lane] = ob;
}

// ---------------------------------------------------------------------------
extern "C" void kernel_launch(void* const* d_in, const int* in_sizes, int n_in,
                              void* d_out, int out_size, void* d_ws, size_t ws_size,
                              hipStream_t stream) {
  const float* h_in = (const float*)d_in[0];
  const int* seg = (const int*)d_in[1];
  const float* Wq = (const float*)d_in[2];
  const float* bq = (const float*)d_in[3];
  const float* Wk = (const float*)d_in[4];
  const float* bk = (const float*)d_in[5];
  const float* Wv = (const float*)d_in[6];
  const float* bv = (const float*)d_in[7];
  const float* Wc = (const float*)d_in[8];
  const float* bc = (const float*)d_in[9];
  const float* Wp = (const float*)d_in[10];
  const float* bp = (const float*)d_in[11];
  const float* g1 = (const float*)d_in[12];
  const float* b1 = (const float*)d_in[13];
  const float* g2 = (const float*)d_in[14];
  const float* b2 = (const float*)d_in[15];
  const float* W1 = (const float*)d_in[16];
  const float* fb1 = (const float*)d_in[17];
  const float* W2 = (const float*)d_in[18];
  const float* fb2 = (const float*)d_in[19];
  float* outp = (float*)d_out;

  char* p = (char*)d_ws;
  auto alloc = [&](size_t bytes) {
    char* r = p;
    p += (bytes + 255) & ~(size_t)255;
    return r;
  };
  unsigned short* wqkvcb = (unsigned short*)alloc((size_t)2048 * 512 * 2);
  unsigned short* wpb = (unsigned short*)alloc((size_t)512 * 512 * 2);
  unsigned short* w1b = (unsigned short*)alloc((size_t)2048 * 512 * 2);
  unsigned short* w2b = (unsigned short*)alloc((size_t)512 * 2048 * 2);
  float* bqkvc = (float*)alloc(2048 * 4);
  unsigned short* hb = (unsigned short*)alloc((size_t)TTOK * 512 * 2);
  unsigned short* qkvcb = (unsigned short*)alloc((size_t)TTOK * 2048 * 2);
  unsigned short* aob = (unsigned short*)alloc((size_t)TTOK * 512 * 2);
  float* xbuf = (float*)alloc((size_t)TTOK * 512 * 4);
  float* h1 = (float*)alloc((size_t)TTOK * 512 * 4);
  unsigned short* h1b = (unsigned short*)alloc((size_t)TTOK * 512 * 2);
  unsigned short* f1b = (unsigned short*)alloc((size_t)TTOK * 2048 * 2);
  float* hcur = (float*)alloc((size_t)TTOK * 512 * 4);
  int* sstart = (int*)alloc(TTOK * 4);
  int* send = (int*)alloc(TTOK * 4);

  dim3 tb(32, 8);
  transpose_cast<<<dim3(16, 16), tb, 0, stream>>>(Wq, wqkvcb + 0 * 512 * 512, 512, 512);
  transpose_cast<<<dim3(16, 16), tb, 0, stream>>>(Wk, wqkvcb + 1 * 512 * 512, 512, 512);
  transpose_cast<<<dim3(16, 16), tb, 0, stream>>>(Wv, wqkvcb + 2 * 512 * 512, 512, 512);
  transpose_cast<<<dim3(16, 16), tb, 0, stream>>>(Wc, wqkvcb + 3 * 512 * 512, 512, 512);
  transpose_cast<<<dim3(16, 16), tb, 0, stream>>>(Wp, wpb, 512, 512);
  transpose_cast<<<dim3(64, 16), tb, 0, stream>>>(W1, w1b, 512, 2048);
  transpose_cast<<<dim3(16, 64), tb, 0, stream>>>(W2, w2b, 2048, 512);
  pack_bias<<<8, 256, 0, stream>>>(bq, bk, bv, bc, bqkvc);
  cast_bf16<<<2048, 256, 0, stream>>>(h_in, hb, TTOK * 512 / 4);
  seg_bounds<<<16, 256, 0, stream>>>(seg, sstart, send, TTOK);

  const float* resp = h_in;
  for (int layer = 0; layer < NLAYER; ++layer) {
    // QKVC projection: [4096,512] x [512,2048]
    gemm_bf16<0><<<dim3(32, 16), 256, 0, stream>>>(hb, wqkvcb, TTOK, 2048, 512,
                                                   bqkvc, nullptr, nullptr, qkvcb);
    // segment-local attention (+c), bf16 out
    attn_kernel<<<dim3(TTOK / 64, NHEAD), 256, 0, stream>>>(qkvcb, sstart, send, aob);
    // attn_out @ Wp + bp + prev  -> xbuf (f32)
    gemm_bf16<1><<<dim3(32, 4), 256, 0, stream>>>(aob, wpb, TTOK, 512, 512,
                                                  bp, resp, xbuf, nullptr);
    ln_kernel<<<TTOK, 64, 0, stream>>>(xbuf, g1, b1, h1, h1b);
    // FFN1: swish(h1 @ W1 + fb1) -> f1b (bf16)
    gemm_bf16<2><<<dim3(32, 16), 256, 0, stream>>>(h1b, w1b, TTOK, 2048, 512,
                                                   fb1, nullptr, nullptr, f1b);
    // FFN2: f1 @ W2 + fb2 + h1 -> xbuf (f32)
    gemm_bf16<1><<<dim3(32, 4), 256, 0, stream>>>(f1b, w2b, TTOK, 512, 2048,
                                                  fb2, h1, xbuf, nullptr);
    float* lnout = (layer == NLAYER - 1) ? outp : hcur;
    ln_kernel<<<TTOK, 64, 0, stream>>>(xbuf, g2, b2, lnout, hb);
    resp = hcur;
  }
}

// Round 6
// 1025.735 us; speedup vs baseline: 2.2750x; 2.2750x over previous
//
#include <hip/hip_runtime.h>
#include <stdint.h>

// Problem constants
#define TTOK 4096
#define DMODEL 512
#define NHEAD 8
#define FFDIM 2048
#define NLAYER 6

typedef short bf16x8 __attribute__((ext_vector_type(8)));
typedef float f32x4 __attribute__((ext_vector_type(4)));

__device__ __forceinline__ unsigned short f2bf(float f) {
  union { float f; unsigned int u; } v; v.f = f;
  unsigned int u = v.u;
  unsigned int r = (u + 0x7FFFu + ((u >> 16) & 1u)) >> 16;
  return (unsigned short)r;
}

__device__ __forceinline__ float bf2f(unsigned short h) {
  union { unsigned int u; float f; } v; v.u = ((unsigned int)h) << 16;
  return v.f;
}

// ---------------------------------------------------------------------------
// Weight prep: transpose + cast f32 [K][N] -> bf16 [N][K]
// ---------------------------------------------------------------------------
__global__ void transpose_cast(const float* __restrict__ src, unsigned short* __restrict__ dst,
                               int K, int N) {
  __shared__ float tile[32][33];
  const int n0 = blockIdx.x * 32, k0 = blockIdx.y * 32;
  const int x = threadIdx.x, y = threadIdx.y;
#pragma unroll
  for (int yy = 0; yy < 32; yy += 8)
    tile[y + yy][x] = src[(size_t)(k0 + y + yy) * N + n0 + x];
  __syncthreads();
#pragma unroll
  for (int yy = 0; yy < 32; yy += 8)
    dst[(size_t)(n0 + y + yy) * K + k0 + x] = f2bf(tile[x][y + yy]);
}

__global__ void pack_bias(const float* __restrict__ bq, const float* __restrict__ bk,
                          const float* __restrict__ bv, const float* __restrict__ bc,
                          float* __restrict__ out) {
  int i = blockIdx.x * 256 + threadIdx.x;
  const float* src = (i < 512) ? bq : (i < 1024) ? bk : (i < 1536) ? bv : bc;
  out[i] = src[i & 511];
}

__global__ void cast_bf16(const float* __restrict__ src, unsigned short* __restrict__ dst, int n4) {
  int i = blockIdx.x * 256 + threadIdx.x;
  if (i < n4) {
    float4 v = ((const float4*)src)[i];
    uint2 o;
    o.x = (unsigned int)f2bf(v.x) | ((unsigned int)f2bf(v.y) << 16);
    o.y = (unsigned int)f2bf(v.z) | ((unsigned int)f2bf(v.w) << 16);
    ((uint2*)dst)[i] = o;
  }
}

__global__ void seg_bounds(const int* __restrict__ seg, int* __restrict__ ss,
                           int* __restrict__ se, int T) {
  const int t = blockIdx.x * 256 + threadIdx.x;
  if (t >= T) return;
  const int sid = seg[t];
  int lo = 0, hi = T;
  while (lo < hi) { int mid = (lo + hi) >> 1; if (seg[mid] < sid) lo = mid + 1; else hi = mid; }
  ss[t] = lo;
  lo = t; hi = T;
  while (lo < hi) { int mid = (lo + hi) >> 1; if (seg[mid] <= sid) lo = mid + 1; else hi = mid; }
  se[t] = lo;
}

// ---------------------------------------------------------------------------
// bf16 MFMA GEMM: C[M,N] = A[M,K] * Bt[N,K]^T  (+bias, optional res/swish)
// MODE 0: out_bf16 = acc + bias
// MODE 1: out_f32  = res + acc + bias
// MODE 2: out_bf16 = swish(acc + bias)
// ---------------------------------------------------------------------------
template <int MODE>
__launch_bounds__(256)
__global__ void gemm_bf16(const unsigned short* __restrict__ A,
                          const unsigned short* __restrict__ Bt,
                          int M, int N, int K,
                          const float* __restrict__ bias,
                          const float* __restrict__ res,
                          float* __restrict__ outF,
                          unsigned short* __restrict__ outB) {
  __shared__ uint4 As[1024];  // 128 rows x 8 x 16B = 16KB
  __shared__ uint4 Bs[1024];
  const int tid = threadIdx.x;
  const int lane = tid & 63;
  const int wv = tid >> 6;
  const int wm = wv >> 1, wn = wv & 1;
  const int l15 = lane & 15, l4 = lane >> 4;
  const int bm0 = blockIdx.x * 128;
  const int bn0 = blockIdx.y * 128;

  f32x4 acc[4][4];
#pragma unroll
  for (int m = 0; m < 4; ++m)
#pragma unroll
    for (int n = 0; n < 4; ++n) acc[m][n] = (f32x4){0.f, 0.f, 0.f, 0.f};

  for (int k0 = 0; k0 < K; k0 += 64) {
#pragma unroll
    for (int i = 0; i < 4; ++i) {
      const int d = tid + i * 256;
      const int r = d >> 3, c = d & 7;
      const uint4 va = *((const uint4*)(A + (size_t)(bm0 + r) * K + k0) + c);
      const uint4 vb = *((const uint4*)(Bt + (size_t)(bn0 + r) * K + k0) + c);
      const int u = r * 8 + (c ^ (r & 7));
      As[u] = va;
      Bs[u] = vb;
    }
    __syncthreads();
#pragma unroll
    for (int kk = 0; kk < 2; ++kk) {
      bf16x8 af[4], bfr[4];
#pragma unroll
      for (int m = 0; m < 4; ++m) {
        const int row = wm * 64 + m * 16 + l15;
        const int c = kk * 4 + l4;
        af[m] = *(const bf16x8*)&As[row * 8 + (c ^ (row & 7))];
      }
#pragma unroll
      for (int n = 0; n < 4; ++n) {
        const int row = wn * 64 + n * 16 + l15;
        const int c = kk * 4 + l4;
        bfr[n] = *(const bf16x8*)&Bs[row * 8 + (c ^ (row & 7))];
      }
#pragma unroll
      for (int m = 0; m < 4; ++m)
#pragma unroll
        for (int n = 0; n < 4; ++n)
          acc[m][n] = __builtin_amdgcn_mfma_f32_16x16x32_bf16(af[m], bfr[n], acc[m][n], 0, 0, 0);
    }
    __syncthreads();
  }

  float bvals[4];
#pragma unroll
  for (int n = 0; n < 4; ++n) bvals[n] = bias[bn0 + wn * 64 + n * 16 + l15];

#pragma unroll
  for (int m = 0; m < 4; ++m) {
#pragma unroll
    for (int r = 0; r < 4; ++r) {
      const int R = bm0 + wm * 64 + m * 16 + l4 * 4 + r;
#pragma unroll
      for (int n = 0; n < 4; ++n) {
        const int C = bn0 + wn * 64 + n * 16 + l15;
        float v = acc[m][n][r] + bvals[n];
        if (MODE == 1) {
          v += res[(size_t)R * N + C];
          outF[(size_t)R * N + C] = v;
        } else if (MODE == 2) {
          v = v / (1.f + __expf(-v));
          outB[(size_t)R * N + C] = f2bf(v);
        } else {
          outB[(size_t)R * N + C] = f2bf(v);
        }
      }
    }
  }
}

// ---------------------------------------------------------------------------
// Segment-local flash attention with MFMA (16x16x32 bf16).
// Block: 256 thr = 4 waves, each wave owns 16 q-rows of a 64-row tile; one head.
// qkvcb: [T][2048] bf16, sections q|k|v|c of 512, head-major inside each.
// Per K-tile (64 keys): S = Q K^T via MFMA (K B-frags direct from global),
// online softmax in-register (rows live in 16-lane groups), P -> LDS (bf16),
// PV via MFMA with V transposed in LDS. Output aob = att@v + c (bf16).
// LDS strides of 72 u16 (=36 words ≡ 4 mod 32) keep b128 column reads
// quarter-wave conflict-clean and scalar writes ~2-way (free).
// ---------------------------------------------------------------------------
__launch_bounds__(256)
__global__ void attn_mfma(const unsigned short* __restrict__ qkvcb,
                          const int* __restrict__ sstart,
                          const int* __restrict__ send,
                          unsigned short* __restrict__ aob) {
  __shared__ unsigned short Vt[64 * 72];       // [d][token], stride 72
  __shared__ unsigned short Pl[4][16 * 72];    // per-wave P [row][key], stride 72
  const int tid = threadIdx.x;
  const int lane = tid & 63;
  const int wq = tid >> 6;
  const int l15 = lane & 15;
  const int g = lane >> 4;
  const int head = blockIdx.y;
  const int q0 = blockIdx.x * 64;

  // Q A-fragments (row = l15, k-slice = g*8..+7 within each 32-k step)
  const int tq = q0 + wq * 16 + l15;
  const size_t qbase = (size_t)tq * 2048 + head * 64;
  bf16x8 qf0 = *(const bf16x8*)(qkvcb + qbase + g * 8);
  bf16x8 qf1 = *(const bf16x8*)(qkvcb + qbase + 32 + g * 8);

  // per-row (C-layout row = 4g+reg) segment bounds
  int sr[4], er[4];
#pragma unroll
  for (int r = 0; r < 4; ++r) {
    const int q = q0 + wq * 16 + 4 * g + r;
    sr[r] = sstart[q];
    er[r] = send[q];
  }
  const int s0 = sstart[q0];
  const int e1 = send[q0 + 63];

  float m_[4], l_[4];
  f32x4 o[4];
#pragma unroll
  for (int r = 0; r < 4; ++r) { m_[r] = -1e30f; l_[r] = 0.f; }
#pragma unroll
  for (int n = 0; n < 4; ++n) o[n] = (f32x4){0.f, 0.f, 0.f, 0.f};

  for (int k0 = s0; k0 < e1; k0 += 64) {
    // ---- stage V transposed: Vt[d][j] = V[k0+j][d] ----
#pragma unroll
    for (int i = 0; i < 2; ++i) {
      const int j = tid & 63;
      const int d8 = (tid >> 6) + 4 * i;
      const int tv = min(k0 + j, TTOK - 1);
      const uint4 u = *(const uint4*)(qkvcb + (size_t)tv * 2048 + 1024 + head * 64 + d8 * 8);
      const unsigned int uu[4] = {u.x, u.y, u.z, u.w};
#pragma unroll
      for (int t = 0; t < 4; ++t) {
        Vt[(d8 * 8 + 2 * t) * 72 + j] = (unsigned short)(uu[t] & 0xFFFFu);
        Vt[(d8 * 8 + 2 * t + 1) * 72 + j] = (unsigned short)(uu[t] >> 16);
      }
    }
    __syncthreads();

    // ---- S = Q K^T (B-frag: col = key token = l15+16n, direct from global) ----
    f32x4 sac[4];
#pragma unroll
    for (int n = 0; n < 4; ++n) {
      const int tk = min(k0 + 16 * n + l15, TTOK - 1);
      const size_t kb = (size_t)tk * 2048 + 512 + head * 64;
      const bf16x8 kf0 = *(const bf16x8*)(qkvcb + kb + g * 8);
      const bf16x8 kf1 = *(const bf16x8*)(qkvcb + kb + 32 + g * 8);
      f32x4 z = (f32x4){0.f, 0.f, 0.f, 0.f};
      z = __builtin_amdgcn_mfma_f32_16x16x32_bf16(qf0, kf0, z, 0, 0, 0);
      sac[n] = __builtin_amdgcn_mfma_f32_16x16x32_bf16(qf1, kf1, z, 0, 0, 0);
    }

    // ---- scale + segment mask + online softmax ----
    float pv[4][4];  // [n][reg]
    float tm[4] = {-1e30f, -1e30f, -1e30f, -1e30f};
#pragma unroll
    for (int n = 0; n < 4; ++n) {
      const int col = k0 + 16 * n + l15;
#pragma unroll
      for (int r = 0; r < 4; ++r) {
        float v = sac[n][r] * 0.125f;
        if (col < sr[r] || col >= er[r]) v = -1e30f;
        pv[n][r] = v;
        tm[r] = fmaxf(tm[r], v);
      }
    }
#pragma unroll
    for (int off = 1; off < 16; off <<= 1) {
#pragma unroll
      for (int r = 0; r < 4; ++r) tm[r] = fmaxf(tm[r], __shfl_xor(tm[r], off));
    }
    float corr[4], psum[4];
#pragma unroll
    for (int r = 0; r < 4; ++r) {
      const float nm = fmaxf(m_[r], tm[r]);
      corr[r] = __expf(m_[r] - nm);
      m_[r] = nm;
      psum[r] = 0.f;
    }
#pragma unroll
    for (int n = 0; n < 4; ++n) {
#pragma unroll
      for (int r = 0; r < 4; ++r) {
        const float p = __expf(pv[n][r] - m_[r]);
        pv[n][r] = p;
        psum[r] += p;
      }
    }
#pragma unroll
    for (int off = 1; off < 16; off <<= 1) {
#pragma unroll
      for (int r = 0; r < 4; ++r) psum[r] += __shfl_xor(psum[r], off);
    }
    f32x4 corrv;
#pragma unroll
    for (int r = 0; r < 4; ++r) {
      l_[r] = l_[r] * corr[r] + psum[r];
      corrv[r] = corr[r];
    }
#pragma unroll
    for (int n = 0; n < 4; ++n) o[n] *= corrv;

    // ---- P -> LDS (bf16), wave-private ----
    unsigned short* pw = &Pl[wq][0];
#pragma unroll
    for (int n = 0; n < 4; ++n)
#pragma unroll
      for (int r = 0; r < 4; ++r)
        pw[(4 * g + r) * 72 + 16 * n + l15] = f2bf(pv[n][r]);

    // ---- O += P @ V ----
    const bf16x8 pa0 = *(const bf16x8*)(pw + l15 * 72 + g * 8);
    const bf16x8 pa1 = *(const bf16x8*)(pw + l15 * 72 + 32 + g * 8);
#pragma unroll
    for (int n = 0; n < 4; ++n) {
      const bf16x8 vb0 = *(const bf16x8*)(Vt + (16 * n + l15) * 72 + g * 8);
      const bf16x8 vb1 = *(const bf16x8*)(Vt + (16 * n + l15) * 72 + 32 + g * 8);
      o[n] = __builtin_amdgcn_mfma_f32_16x16x32_bf16(pa0, vb0, o[n], 0, 0, 0);
      o[n] = __builtin_amdgcn_mfma_f32_16x16x32_bf16(pa1, vb1, o[n], 0, 0, 0);
    }
    __syncthreads();
  }

  // ---- normalize, add c, store ----
  float rl[4];
#pragma unroll
  for (int r = 0; r < 4; ++r) rl[r] = 1.f / l_[r];
#pragma unroll
  for (int n = 0; n < 4; ++n) {
#pragma unroll
    for (int r = 0; r < 4; ++r) {
      const int q = q0 + wq * 16 + 4 * g + r;
      const int d = head * 64 + 16 * n + l15;
      const float cv = bf2f(qkvcb[(size_t)q * 2048 + 1536 + d]);
      aob[(size_t)q * 512 + d] = f2bf(o[n][r] * rl[r] + cv);
    }
  }
}

// ---------------------------------------------------------------------------
// TF-style LayerNorm over D=512: out = g*(x-u)/sqrt(var+1e-12)+b
// ---------------------------------------------------------------------------
__launch_bounds__(64)
__global__ void ln_kernel(const float* __restrict__ x, const float* __restrict__ g,
                          const float* __restrict__ b, float* __restrict__ outF,
                          unsigned short* __restrict__ outB) {
  const int row = blockIdx.x;
  const int lane = threadIdx.x;
  const float4* xr = (const float4*)(x + (size_t)row * 512);
  float4 a = xr[lane * 2], c = xr[lane * 2 + 1];
  float s = a.x + a.y + a.z + a.w + c.x + c.y + c.z + c.w;
  float sq = a.x * a.x + a.y * a.y + a.z * a.z + a.w * a.w +
             c.x * c.x + c.y * c.y + c.z * c.z + c.w * c.w;
#pragma unroll
  for (int off = 1; off < 64; off <<= 1) {
    s += __shfl_xor(s, off);
    sq += __shfl_xor(sq, off);
  }
  const float mean = s * (1.f / 512.f);
  const float var = sq * (1.f / 512.f) - mean * mean;
  const float rstd = rsqrtf(var + 1e-12f);
  const float4* gr = (const float4*)g;
  const float4* br = (const float4*)b;
  float4 g0 = gr[lane * 2], g1v = gr[lane * 2 + 1];
  float4 b0 = br[lane * 2], b1v = br[lane * 2 + 1];
  float4 y0, y1;
  y0.x = (a.x - mean) * rstd * g0.x + b0.x;
  y0.y = (a.y - mean) * rstd * g0.y + b0.y;
  y0.z = (a.z - mean) * rstd * g0.z + b0.z;
  y0.w = (a.w - mean) * rstd * g0.w + b0.w;
  y1.x = (c.x - mean) * rstd * g1v.x + b1v.x;
  y1.y = (c.y - mean) * rstd * g1v.y + b1v.y;
  y1.z = (c.z - mean) * rstd * g1v.z + b1v.z;
  y1.w = (c.w - mean) * rstd * g1v.w + b1v.w;
  float4* of = (float4*)(outF + (size_t)row * 512);
  of[lane * 2] = y0;
  of[lane * 2 + 1] = y1;
  uint4 ob;
  ob.x = (unsigned int)f2bf(y0.x) | ((unsigned int)f2bf(y0.y) << 16);
  ob.y = (unsigned int)f2bf(y0.z) | ((unsigned int)f2bf(y0.w) << 16);
  ob.z = (unsigned int)f2bf(y1.x) | ((unsigned int)f2bf(y1.y) << 16);
  ob.w = (unsigned int)f2bf(y1.z) | ((unsigned int)f2bf(y1.w) << 16);
  ((uint4*)(outB + (size_t)row * 512))[lane] = ob;
}

// ---------------------------------------------------------------------------
extern "C" void kernel_launch(void* const* d_in, const int* in_sizes, int n_in,
                              void* d_out, int out_size, void* d_ws, size_t ws_size,
                              hipStream_t stream) {
  const float* h_in = (const float*)d_in[0];
  const int* seg = (const int*)d_in[1];
  const float* Wq = (const float*)d_in[2];
  const float* bq = (const float*)d_in[3];
  const float* Wk = (const float*)d_in[4];
  const float* bk = (const float*)d_in[5];
  const float* Wv = (const float*)d_in[6];
  const float* bv = (const float*)d_in[7];
  const float* Wc = (const float*)d_in[8];
  const float* bc = (const float*)d_in[9];
  const float* Wp = (const float*)d_in[10];
  const float* bp = (const float*)d_in[11];
  const float* g1 = (const float*)d_in[12];
  const float* b1 = (const float*)d_in[13];
  const float* g2 = (const float*)d_in[14];
  const float* b2 = (const float*)d_in[15];
  const float* W1 = (const float*)d_in[16];
  const float* fb1 = (const float*)d_in[17];
  const float* W2 = (const float*)d_in[18];
  const float* fb2 = (const float*)d_in[19];
  float* outp = (float*)d_out;

  char* p = (char*)d_ws;
  auto alloc = [&](size_t bytes) {
    char* r = p;
    p += (bytes + 255) & ~(size_t)255;
    return r;
  };
  unsigned short* wqkvcb = (unsigned short*)alloc((size_t)2048 * 512 * 2);
  unsigned short* wpb = (unsigned short*)alloc((size_t)512 * 512 * 2);
  unsigned short* w1b = (unsigned short*)alloc((size_t)2048 * 512 * 2);
  unsigned short* w2b = (unsigned short*)alloc((size_t)512 * 2048 * 2);
  float* bqkvc = (float*)alloc(2048 * 4);
  unsigned short* hb = (unsigned short*)alloc((size_t)TTOK * 512 * 2);
  unsigned short* qkvcb = (unsigned short*)alloc((size_t)TTOK * 2048 * 2);
  unsigned short* aob = (unsigned short*)alloc((size_t)TTOK * 512 * 2);
  float* xbuf = (float*)alloc((size_t)TTOK * 512 * 4);
  float* h1 = (float*)alloc((size_t)TTOK * 512 * 4);
  unsigned short* h1b = (unsigned short*)alloc((size_t)TTOK * 512 * 2);
  unsigned short* f1b = (unsigned short*)alloc((size_t)TTOK * 2048 * 2);
  float* hcur = (float*)alloc((size_t)TTOK * 512 * 4);
  int* sstart = (int*)alloc(TTOK * 4);
  int* send = (int*)alloc(TTOK * 4);

  dim3 tb(32, 8);
  transpose_cast<<<dim3(16, 16), tb, 0, stream>>>(Wq, wqkvcb + 0 * 512 * 512, 512, 512);
  transpose_cast<<<dim3(16, 16), tb, 0, stream>>>(Wk, wqkvcb + 1 * 512 * 512, 512, 512);
  transpose_cast<<<dim3(16, 16), tb, 0, stream>>>(Wv, wqkvcb + 2 * 512 * 512, 512, 512);
  transpose_cast<<<dim3(16, 16), tb, 0, stream>>>(Wc, wqkvcb + 3 * 512 * 512, 512, 512);
  transpose_cast<<<dim3(16, 16), tb, 0, stream>>>(Wp, wpb, 512, 512);
  transpose_cast<<<dim3(64, 16), tb, 0, stream>>>(W1, w1b, 512, 2048);
  transpose_cast<<<dim3(16, 64), tb, 0, stream>>>(W2, w2b, 2048, 512);
  pack_bias<<<8, 256, 0, stream>>>(bq, bk, bv, bc, bqkvc);
  cast_bf16<<<2048, 256, 0, stream>>>(h_in, hb, TTOK * 512 / 4);
  seg_bounds<<<16, 256, 0, stream>>>(seg, sstart, send, TTOK);

  const float* resp = h_in;
  for (int layer = 0; layer < NLAYER; ++layer) {
    // QKVC projection: [4096,512] x [512,2048]
    gemm_bf16<0><<<dim3(32, 16), 256, 0, stream>>>(hb, wqkvcb, TTOK, 2048, 512,
                                                   bqkvc, nullptr, nullptr, qkvcb);
    // segment-local MFMA flash attention (+c), bf16 out
    attn_mfma<<<dim3(TTOK / 64, NHEAD), 256, 0, stream>>>(qkvcb, sstart, send, aob);
    // attn_out @ Wp + bp + prev  -> xbuf (f32)
    gemm_bf16<1><<<dim3(32, 4), 256, 0, stream>>>(aob, wpb, TTOK, 512, 512,
                                                  bp, resp, xbuf, nullptr);
    ln_kernel<<<TTOK, 64, 0, stream>>>(xbuf, g1, b1, h1, h1b);
    // FFN1: swish(h1 @ W1 + fb1) -> f1b (bf16)
    gemm_bf16<2><<<dim3(32, 16), 256, 0, stream>>>(h1b, w1b, TTOK, 2048, 512,
                                                   fb1, nullptr, nullptr, f1b);
    // FFN2: f1 @ W2 + fb2 + h1 -> xbuf (f32)
    gemm_bf16<1><<<dim3(32, 4), 256, 0, stream>>>(f1b, w2b, TTOK, 512, 2048,
                                                  fb2, h1, xbuf, nullptr);
    float* lnout = (layer == NLAYER - 1) ? outp : hcur;
    ln_kernel<<<TTOK, 64, 0, stream>>>(xbuf, g2, b2, lnout, hb);
    resp = hcur;
  }
}

// Round 7
// 945.657 us; speedup vs baseline: 2.4676x; 1.0847x over previous
//
#include <hip/hip_runtime.h>
#include <stdint.h>

// Problem constants
#define TTOK 4096
#define DMODEL 512
#define NHEAD 8
#define FFDIM 2048
#define NLAYER 6

typedef short bf16x8 __attribute__((ext_vector_type(8)));
typedef float f32x4 __attribute__((ext_vector_type(4)));

__device__ __forceinline__ unsigned short f2bf(float f) {
  union { float f; unsigned int u; } v; v.f = f;
  unsigned int u = v.u;
  unsigned int r = (u + 0x7FFFu + ((u >> 16) & 1u)) >> 16;
  return (unsigned short)r;
}

__device__ __forceinline__ float bf2f(unsigned short h) {
  union { unsigned int u; float f; } v; v.u = ((unsigned int)h) << 16;
  return v.f;
}

// global -> LDS direct (16B per lane). LDS dest must be wave-uniform base;
// lane writes base + lane*16. Source is per-lane (pre-swizzled).
#define GLOAD_LDS16(gp, lp)                                                      \
  __builtin_amdgcn_global_load_lds(                                              \
      (const __attribute__((address_space(1))) unsigned int*)(gp),               \
      (__attribute__((address_space(3))) unsigned int*)(lp), 16, 0, 0)

// ---------------------------------------------------------------------------
// Weight prep: transpose + cast f32 [K][N] -> bf16 [N][K]
// ---------------------------------------------------------------------------
__global__ void transpose_cast(const float* __restrict__ src, unsigned short* __restrict__ dst,
                               int K, int N) {
  __shared__ float tile[32][33];
  const int n0 = blockIdx.x * 32, k0 = blockIdx.y * 32;
  const int x = threadIdx.x, y = threadIdx.y;
#pragma unroll
  for (int yy = 0; yy < 32; yy += 8)
    tile[y + yy][x] = src[(size_t)(k0 + y + yy) * N + n0 + x];
  __syncthreads();
#pragma unroll
  for (int yy = 0; yy < 32; yy += 8)
    dst[(size_t)(n0 + y + yy) * K + k0 + x] = f2bf(tile[x][y + yy]);
}

__global__ void pack_bias(const float* __restrict__ bq, const float* __restrict__ bk,
                          const float* __restrict__ bv, const float* __restrict__ bc,
                          float* __restrict__ out) {
  int i = blockIdx.x * 256 + threadIdx.x;
  const float* src = (i < 512) ? bq : (i < 1024) ? bk : (i < 1536) ? bv : bc;
  out[i] = src[i & 511];
}

__global__ void cast_bf16(const float* __restrict__ src, unsigned short* __restrict__ dst, int n4) {
  int i = blockIdx.x * 256 + threadIdx.x;
  if (i < n4) {
    float4 v = ((const float4*)src)[i];
    uint2 o;
    o.x = (unsigned int)f2bf(v.x) | ((unsigned int)f2bf(v.y) << 16);
    o.y = (unsigned int)f2bf(v.z) | ((unsigned int)f2bf(v.w) << 16);
    ((uint2*)dst)[i] = o;
  }
}

__global__ void seg_bounds(const int* __restrict__ seg, int* __restrict__ ss,
                           int* __restrict__ se, int T) {
  const int t = blockIdx.x * 256 + threadIdx.x;
  if (t >= T) return;
  const int sid = seg[t];
  int lo = 0, hi = T;
  while (lo < hi) { int mid = (lo + hi) >> 1; if (seg[mid] < sid) lo = mid + 1; else hi = mid; }
  ss[t] = lo;
  lo = t; hi = T;
  while (lo < hi) { int mid = (lo + hi) >> 1; if (seg[mid] <= sid) lo = mid + 1; else hi = mid; }
  se[t] = lo;
}

// ---------------------------------------------------------------------------
// bf16 MFMA GEMM: C[M,N] = A[M,K] * Bt[N,K]^T  (+bias, optional res/swish)
// MODE 0: out_bf16 = acc + bias
// MODE 1: out_f32  = res + acc + bias
// MODE 2: out_bf16 = swish(acc + bias)
// MF = m-fragments per wave; BM = MF*32 (128 or 64). BN = 128, BK = 64.
// Staging via global_load_lds (linear LDS dest, inverse-swizzled source so
// fragment reads use unit c ^ (row&7) — XOR involution both sides).
// ---------------------------------------------------------------------------
template <int MODE, int MF>
__launch_bounds__(256)
__global__ void gemm_bf16(const unsigned short* __restrict__ A,
                          const unsigned short* __restrict__ Bt,
                          int M, int N, int K,
                          const float* __restrict__ bias,
                          const float* __restrict__ res,
                          float* __restrict__ outF,
                          unsigned short* __restrict__ outB) {
  __shared__ uint4 As[MF * 256];  // BM rows x 8 x 16B
  __shared__ uint4 Bs[1024];      // 128 rows x 8 x 16B
  const int tid = threadIdx.x;
  const int lane = tid & 63;
  const int wv = tid >> 6;
  const int wm = wv >> 1, wn = wv & 1;
  const int l15 = lane & 15, l4 = lane >> 4;
  const int bm0 = blockIdx.x * (MF * 32);
  const int bn0 = blockIdx.y * 128;

  f32x4 acc[MF][4];
#pragma unroll
  for (int m = 0; m < MF; ++m)
#pragma unroll
    for (int n = 0; n < 4; ++n) acc[m][n] = (f32x4){0.f, 0.f, 0.f, 0.f};

  for (int k0 = 0; k0 < K; k0 += 64) {
#pragma unroll
    for (int i = 0; i < MF; ++i) {
      const int u = tid + i * 256;
      const int r = u >> 3;
      const int c = (u & 7) ^ (r & 7);
      GLOAD_LDS16(A + (size_t)(bm0 + r) * K + k0 + c * 8, &As[i * 256 + wv * 64]);
    }
#pragma unroll
    for (int i = 0; i < 4; ++i) {
      const int u = tid + i * 256;
      const int r = u >> 3;
      const int c = (u & 7) ^ (r & 7);
      GLOAD_LDS16(Bt + (size_t)(bn0 + r) * K + k0 + c * 8, &Bs[i * 256 + wv * 64]);
    }
    __syncthreads();
#pragma unroll
    for (int kk = 0; kk < 2; ++kk) {
      bf16x8 af[MF], bfr[4];
#pragma unroll
      for (int m = 0; m < MF; ++m) {
        const int row = wm * (MF * 16) + m * 16 + l15;
        const int c = kk * 4 + l4;
        af[m] = *(const bf16x8*)&As[row * 8 + (c ^ (row & 7))];
      }
#pragma unroll
      for (int n = 0; n < 4; ++n) {
        const int row = wn * 64 + n * 16 + l15;
        const int c = kk * 4 + l4;
        bfr[n] = *(const bf16x8*)&Bs[row * 8 + (c ^ (row & 7))];
      }
#pragma unroll
      for (int m = 0; m < MF; ++m)
#pragma unroll
        for (int n = 0; n < 4; ++n)
          acc[m][n] = __builtin_amdgcn_mfma_f32_16x16x32_bf16(af[m], bfr[n], acc[m][n], 0, 0, 0);
    }
    __syncthreads();
  }

  float bvals[4];
#pragma unroll
  for (int n = 0; n < 4; ++n) bvals[n] = bias[bn0 + wn * 64 + n * 16 + l15];

#pragma unroll
  for (int m = 0; m < MF; ++m) {
#pragma unroll
    for (int r = 0; r < 4; ++r) {
      const int R = bm0 + wm * (MF * 16) + m * 16 + l4 * 4 + r;
#pragma unroll
      for (int n = 0; n < 4; ++n) {
        const int C = bn0 + wn * 64 + n * 16 + l15;
        float v = acc[m][n][r] + bvals[n];
        if (MODE == 1) {
          v += res[(size_t)R * N + C];
          outF[(size_t)R * N + C] = v;
        } else if (MODE == 2) {
          v = v / (1.f + __expf(-v));
          outB[(size_t)R * N + C] = f2bf(v);
        } else {
          outB[(size_t)R * N + C] = f2bf(v);
        }
      }
    }
  }
}

// ---------------------------------------------------------------------------
// Segment-local flash attention, MFMA, ONE WAVE PER BLOCK (zero barriers).
// Grid: (T/16, H). Each wave: 16 q-rows x one head. K-tile = 64 keys.
// Pipeline per tile: write staged V->LDS(buf), QK^T (prefetched K frags),
// issue next tile's V+K global loads (reuse regs), softmax, P->LDS, PV.
// LDS stride 68 u16: transpose scalar writes conflict-free (word = lane>>1
// + const, 32 distinct banks); b128 reads 2-way (free).
// ---------------------------------------------------------------------------
__launch_bounds__(64, 2)
__global__ void attn_mfma(const unsigned short* __restrict__ qkvcb,
                          const int* __restrict__ sstart,
                          const int* __restrict__ send,
                          unsigned short* __restrict__ aob) {
  __shared__ unsigned short Vt[2][64 * 68];  // [buf][d][token]
  __shared__ unsigned short Pl[16 * 68];     // [row][key]
  const int lane = threadIdx.x;
  const int l15 = lane & 15;
  const int g = lane >> 4;
  const int head = blockIdx.y;
  const int q0 = blockIdx.x * 16;

  // Q A-fragments (row = l15, k-slice = g*8..+7 per 32-k step)
  const size_t qbase = (size_t)(q0 + l15) * 2048 + head * 64;
  const bf16x8 qf0 = *(const bf16x8*)(qkvcb + qbase + g * 8);
  const bf16x8 qf1 = *(const bf16x8*)(qkvcb + qbase + 32 + g * 8);

  int sr[4], er[4];
#pragma unroll
  for (int r = 0; r < 4; ++r) {
    const int q = q0 + 4 * g + r;
    sr[r] = sstart[q];
    er[r] = send[q];
  }
  const int s0 = sstart[q0];
  const int e1 = send[q0 + 15];

  // staged V rows (lane = token) and K fragments, reused across tiles
  uint4 vreg[8];
  bf16x8 kfa[4], kfb[4];

  auto LOADV = [&](int k0) {
    const unsigned short* vrow =
        qkvcb + (size_t)min(k0 + lane, TTOK - 1) * 2048 + 1024 + head * 64;
#pragma unroll
    for (int d8 = 0; d8 < 8; ++d8) vreg[d8] = *(const uint4*)(vrow + d8 * 8);
  };
  auto LOADK = [&](int k0) {
#pragma unroll
    for (int n = 0; n < 4; ++n) {
      const size_t kb =
          (size_t)min(k0 + 16 * n + l15, TTOK - 1) * 2048 + 512 + head * 64;
      kfa[n] = *(const bf16x8*)(qkvcb + kb + g * 8);
      kfb[n] = *(const bf16x8*)(qkvcb + kb + 32 + g * 8);
    }
  };
  LOADV(s0);
  LOADK(s0);

  float m_[4], l_[4];
  f32x4 o[4];
#pragma unroll
  for (int r = 0; r < 4; ++r) { m_[r] = -1e30f; l_[r] = 0.f; }
#pragma unroll
  for (int n = 0; n < 4; ++n) o[n] = (f32x4){0.f, 0.f, 0.f, 0.f};

  int buf = 0;
  for (int k0 = s0; k0 < e1; k0 += 64, buf ^= 1) {
    // ---- (a) staged V regs -> Vt[buf] (transpose; conflict-free writes) ----
    unsigned short* vb = &Vt[buf][0];
#pragma unroll
    for (int d8 = 0; d8 < 8; ++d8) {
      const unsigned int uu[4] = {vreg[d8].x, vreg[d8].y, vreg[d8].z, vreg[d8].w};
#pragma unroll
      for (int t2 = 0; t2 < 4; ++t2) {
        vb[(d8 * 8 + 2 * t2) * 68 + lane] = (unsigned short)(uu[t2] & 0xFFFFu);
        vb[(d8 * 8 + 2 * t2 + 1) * 68 + lane] = (unsigned short)(uu[t2] >> 16);
      }
    }

    // ---- (b) S = Q K^T (consume prefetched K frags) ----
    f32x4 sac[4];
#pragma unroll
    for (int n = 0; n < 4; ++n) {
      f32x4 z = (f32x4){0.f, 0.f, 0.f, 0.f};
      z = __builtin_amdgcn_mfma_f32_16x16x32_bf16(qf0, kfa[n], z, 0, 0, 0);
      sac[n] = __builtin_amdgcn_mfma_f32_16x16x32_bf16(qf1, kfb[n], z, 0, 0, 0);
    }

    // ---- (c) issue next tile's loads (regs free after (a)/(b)) ----
    const int k0n = (k0 + 64 < e1) ? (k0 + 64) : s0;
    LOADV(k0n);
    LOADK(k0n);

    // ---- (d) scale + segment mask + online softmax ----
    float pv[4][4];  // [n][reg]
    float tm[4] = {-1e30f, -1e30f, -1e30f, -1e30f};
#pragma unroll
    for (int n = 0; n < 4; ++n) {
      const int col = k0 + 16 * n + l15;
#pragma unroll
      for (int r = 0; r < 4; ++r) {
        float v = sac[n][r] * 0.125f;
        if (col < sr[r] || col >= er[r]) v = -1e30f;
        pv[n][r] = v;
        tm[r] = fmaxf(tm[r], v);
      }
    }
#pragma unroll
    for (int off = 1; off < 16; off <<= 1) {
#pragma unroll
      for (int r = 0; r < 4; ++r) tm[r] = fmaxf(tm[r], __shfl_xor(tm[r], off));
    }
    float corr[4], psum[4];
#pragma unroll
    for (int r = 0; r < 4; ++r) {
      const float nm = fmaxf(m_[r], tm[r]);
      corr[r] = __expf(m_[r] - nm);
      m_[r] = nm;
      psum[r] = 0.f;
    }
#pragma unroll
    for (int n = 0; n < 4; ++n) {
#pragma unroll
      for (int r = 0; r < 4; ++r) {
        const float p = __expf(pv[n][r] - m_[r]);
        pv[n][r] = p;
        psum[r] += p;
      }
    }
#pragma unroll
    for (int off = 1; off < 16; off <<= 1) {
#pragma unroll
      for (int r = 0; r < 4; ++r) psum[r] += __shfl_xor(psum[r], off);
    }
    f32x4 corrv;
#pragma unroll
    for (int r = 0; r < 4; ++r) {
      l_[r] = l_[r] * corr[r] + psum[r];
      corrv[r] = corr[r];
    }
#pragma unroll
    for (int n = 0; n < 4; ++n) o[n] *= corrv;

    // ---- (e) P -> LDS, read A-frags, PV from Vt[buf] ----
#pragma unroll
    for (int n = 0; n < 4; ++n)
#pragma unroll
      for (int r = 0; r < 4; ++r)
        Pl[(4 * g + r) * 68 + 16 * n + l15] = f2bf(pv[n][r]);

    const bf16x8 pa0 = *(const bf16x8*)(Pl + l15 * 68 + g * 8);
    const bf16x8 pa1 = *(const bf16x8*)(Pl + l15 * 68 + 32 + g * 8);
#pragma unroll
    for (int n = 0; n < 4; ++n) {
      const bf16x8 vb0 = *(const bf16x8*)(vb + (16 * n + l15) * 68 + g * 8);
      const bf16x8 vb1 = *(const bf16x8*)(vb + (16 * n + l15) * 68 + 32 + g * 8);
      o[n] = __builtin_amdgcn_mfma_f32_16x16x32_bf16(pa0, vb0, o[n], 0, 0, 0);
      o[n] = __builtin_amdgcn_mfma_f32_16x16x32_bf16(pa1, vb1, o[n], 0, 0, 0);
    }
  }

  // ---- normalize, add c, store ----
  float rl[4];
#pragma unroll
  for (int r = 0; r < 4; ++r) rl[r] = 1.f / l_[r];
#pragma unroll
  for (int n = 0; n < 4; ++n) {
#pragma unroll
    for (int r = 0; r < 4; ++r) {
      const int q = q0 + 4 * g + r;
      const int d = head * 64 + 16 * n + l15;
      const float cv = bf2f(qkvcb[(size_t)q * 2048 + 1536 + d]);
      aob[(size_t)q * 512 + d] = f2bf(o[n][r] * rl[r] + cv);
    }
  }
}

// ---------------------------------------------------------------------------
// TF-style LayerNorm over D=512: out = g*(x-u)/sqrt(var+1e-12)+b
// ---------------------------------------------------------------------------
__launch_bounds__(64)
__global__ void ln_kernel(const float* __restrict__ x, const float* __restrict__ g,
                          const float* __restrict__ b, float* __restrict__ outF,
                          unsigned short* __restrict__ outB) {
  const int row = blockIdx.x;
  const int lane = threadIdx.x;
  const float4* xr = (const float4*)(x + (size_t)row * 512);
  float4 a = xr[lane * 2], c = xr[lane * 2 + 1];
  float s = a.x + a.y + a.z + a.w + c.x + c.y + c.z + c.w;
  float sq = a.x * a.x + a.y * a.y + a.z * a.z + a.w * a.w +
             c.x * c.x + c.y * c.y + c.z * c.z + c.w * c.w;
#pragma unroll
  for (int off = 1; off < 64; off <<= 1) {
    s += __shfl_xor(s, off);
    sq += __shfl_xor(sq, off);
  }
  const float mean = s * (1.f / 512.f);
  const float var = sq * (1.f / 512.f) - mean * mean;
  const float rstd = rsqrtf(var + 1e-12f);
  const float4* gr = (const float4*)g;
  const float4* br = (const float4*)b;
  float4 g0 = gr[lane * 2], g1v = gr[lane * 2 + 1];
  float4 b0 = br[lane * 2], b1v = br[lane * 2 + 1];
  float4 y0, y1;
  y0.x = (a.x - mean) * rstd * g0.x + b0.x;
  y0.y = (a.y - mean) * rstd * g0.y + b0.y;
  y0.z = (a.z - mean) * rstd * g0.z + b0.z;
  y0.w = (a.w - mean) * rstd * g0.w + b0.w;
  y1.x = (c.x - mean) * rstd * g1v.x + b1v.x;
  y1.y = (c.y - mean) * rstd * g1v.y + b1v.y;
  y1.z = (c.z - mean) * rstd * g1v.z + b1v.z;
  y1.w = (c.w - mean) * rstd * g1v.w + b1v.w;
  float4* of = (float4*)(outF + (size_t)row * 512);
  of[lane * 2] = y0;
  of[lane * 2 + 1] = y1;
  uint4 ob;
  ob.x = (unsigned int)f2bf(y0.x) | ((unsigned int)f2bf(y0.y) << 16);
  ob.y = (unsigned int)f2bf(y0.z) | ((unsigned int)f2bf(y0.w) << 16);
  ob.z = (unsigned int)f2bf(y1.x) | ((unsigned int)f2bf(y1.y) << 16);
  ob.w = (unsigned int)f2bf(y1.z) | ((unsigned int)f2bf(y1.w) << 16);
  ((uint4*)(outB + (size_t)row * 512))[lane] = ob;
}

// ---------------------------------------------------------------------------
extern "C" void kernel_launch(void* const* d_in, const int* in_sizes, int n_in,
                              void* d_out, int out_size, void* d_ws, size_t ws_size,
                              hipStream_t stream) {
  const float* h_in = (const float*)d_in[0];
  const int* seg = (const int*)d_in[1];
  const float* Wq = (const float*)d_in[2];
  const float* bq = (const float*)d_in[3];
  const float* Wk = (const float*)d_in[4];
  const float* bk = (const float*)d_in[5];
  const float* Wv = (const float*)d_in[6];
  const float* bv = (const float*)d_in[7];
  const float* Wc = (const float*)d_in[8];
  const float* bc = (const float*)d_in[9];
  const float* Wp = (const float*)d_in[10];
  const float* bp = (const float*)d_in[11];
  const float* g1 = (const float*)d_in[12];
  const float* b1 = (const float*)d_in[13];
  const float* g2 = (const float*)d_in[14];
  const float* b2 = (const float*)d_in[15];
  const float* W1 = (const float*)d_in[16];
  const float* fb1 = (const float*)d_in[17];
  const float* W2 = (const float*)d_in[18];
  const float* fb2 = (const float*)d_in[19];
  float* outp = (float*)d_out;

  char* p = (char*)d_ws;
  auto alloc = [&](size_t bytes) {
    char* r = p;
    p += (bytes + 255) & ~(size_t)255;
    return r;
  };
  unsigned short* wqkvcb = (unsigned short*)alloc((size_t)2048 * 512 * 2);
  unsigned short* wpb = (unsigned short*)alloc((size_t)512 * 512 * 2);
  unsigned short* w1b = (unsigned short*)alloc((size_t)2048 * 512 * 2);
  unsigned short* w2b = (unsigned short*)alloc((size_t)512 * 2048 * 2);
  float* bqkvc = (float*)alloc(2048 * 4);
  unsigned short* hb = (unsigned short*)alloc((size_t)TTOK * 512 * 2);
  unsigned short* qkvcb = (unsigned short*)alloc((size_t)TTOK * 2048 * 2);
  unsigned short* aob = (unsigned short*)alloc((size_t)TTOK * 512 * 2);
  float* xbuf = (float*)alloc((size_t)TTOK * 512 * 4);
  float* h1 = (float*)alloc((size_t)TTOK * 512 * 4);
  unsigned short* h1b = (unsigned short*)alloc((size_t)TTOK * 512 * 2);
  unsigned short* f1b = (unsigned short*)alloc((size_t)TTOK * 2048 * 2);
  float* hcur = (float*)alloc((size_t)TTOK * 512 * 4);
  int* sstart = (int*)alloc(TTOK * 4);
  int* send = (int*)alloc(TTOK * 4);

  dim3 tb(32, 8);
  transpose_cast<<<dim3(16, 16), tb, 0, stream>>>(Wq, wqkvcb + 0 * 512 * 512, 512, 512);
  transpose_cast<<<dim3(16, 16), tb, 0, stream>>>(Wk, wqkvcb + 1 * 512 * 512, 512, 512);
  transpose_cast<<<dim3(16, 16), tb, 0, stream>>>(Wv, wqkvcb + 2 * 512 * 512, 512, 512);
  transpose_cast<<<dim3(16, 16), tb, 0, stream>>>(Wc, wqkvcb + 3 * 512 * 512, 512, 512);
  transpose_cast<<<dim3(16, 16), tb, 0, stream>>>(Wp, wpb, 512, 512);
  transpose_cast<<<dim3(64, 16), tb, 0, stream>>>(W1, w1b, 512, 2048);
  transpose_cast<<<dim3(16, 64), tb, 0, stream>>>(W2, w2b, 2048, 512);
  pack_bias<<<8, 256, 0, stream>>>(bq, bk, bv, bc, bqkvc);
  cast_bf16<<<2048, 256, 0, stream>>>(h_in, hb, TTOK * 512 / 4);
  seg_bounds<<<16, 256, 0, stream>>>(seg, sstart, send, TTOK);

  const float* resp = h_in;
  for (int layer = 0; layer < NLAYER; ++layer) {
    // QKVC projection: [4096,512] x [512,2048]
    gemm_bf16<0, 4><<<dim3(32, 16), 256, 0, stream>>>(hb, wqkvcb, TTOK, 2048, 512,
                                                      bqkvc, nullptr, nullptr, qkvcb);
    // segment-local MFMA flash attention (+c), bf16 out
    attn_mfma<<<dim3(TTOK / 16, NHEAD), 64, 0, stream>>>(qkvcb, sstart, send, aob);
    // attn_out @ Wp + bp + prev  -> xbuf (f32)
    gemm_bf16<1, 2><<<dim3(64, 4), 256, 0, stream>>>(aob, wpb, TTOK, 512, 512,
                                                     bp, resp, xbuf, nullptr);
    ln_kernel<<<TTOK, 64, 0, stream>>>(xbuf, g1, b1, h1, h1b);
    // FFN1: swish(h1 @ W1 + fb1) -> f1b (bf16)
    gemm_bf16<2, 4><<<dim3(32, 16), 256, 0, stream>>>(h1b, w1b, TTOK, 2048, 512,
                                                      fb1, nullptr, nullptr, f1b);
    // FFN2: f1 @ W2 + fb2 + h1 -> xbuf (f32)
    gemm_bf16<1, 2><<<dim3(64, 4), 256, 0, stream>>>(f1b, w2b, TTOK, 512, 2048,
                                                     fb2, h1, xbuf, nullptr);
    float* lnout = (layer == NLAYER - 1) ? outp : hcur;
    ln_kernel<<<TTOK, 64, 0, stream>>>(xbuf, g2, b2, lnout, hb);
    resp = hcur;
  }
}

// Round 8
// 843.244 us; speedup vs baseline: 2.7673x; 1.1215x over previous
//
#include <hip/hip_runtime.h>
#include <stdint.h>

// Problem constants
#define TTOK 4096
#define DMODEL 512
#define NHEAD 8
#define FFDIM 2048
#define NLAYER 6

typedef short bf16x8 __attribute__((ext_vector_type(8)));
typedef float f32x4 __attribute__((ext_vector_type(4)));

__device__ __forceinline__ unsigned short f2bf(float f) {
  union { float f; unsigned int u; } v; v.f = f;
  unsigned int u = v.u;
  unsigned int r = (u + 0x7FFFu + ((u >> 16) & 1u)) >> 16;
  return (unsigned short)r;
}

__device__ __forceinline__ float bf2f(unsigned short h) {
  union { unsigned int u; float f; } v; v.u = ((unsigned int)h) << 16;
  return v.f;
}

// global -> LDS direct (16B per lane). LDS dest must be wave-uniform base;
// lane writes base + lane*16. Source is per-lane (pre-swizzled).
#define GLOAD_LDS16(gp, lp)                                                      \
  __builtin_amdgcn_global_load_lds(                                              \
      (const __attribute__((address_space(1))) unsigned int*)(gp),               \
      (__attribute__((address_space(3))) unsigned int*)(lp), 16, 0, 0)

// ---------------------------------------------------------------------------
// Weight prep: transpose + cast f32 [K][N] -> bf16 [N][K]
// ---------------------------------------------------------------------------
__global__ void transpose_cast(const float* __restrict__ src, unsigned short* __restrict__ dst,
                               int K, int N) {
  __shared__ float tile[32][33];
  const int n0 = blockIdx.x * 32, k0 = blockIdx.y * 32;
  const int x = threadIdx.x, y = threadIdx.y;
#pragma unroll
  for (int yy = 0; yy < 32; yy += 8)
    tile[y + yy][x] = src[(size_t)(k0 + y + yy) * N + n0 + x];
  __syncthreads();
#pragma unroll
  for (int yy = 0; yy < 32; yy += 8)
    dst[(size_t)(n0 + y + yy) * K + k0 + x] = f2bf(tile[x][y + yy]);
}

__global__ void pack_bias(const float* __restrict__ bq, const float* __restrict__ bk,
                          const float* __restrict__ bv, const float* __restrict__ bc,
                          float* __restrict__ out) {
  int i = blockIdx.x * 256 + threadIdx.x;
  const float* src = (i < 512) ? bq : (i < 1024) ? bk : (i < 1536) ? bv : bc;
  out[i] = src[i & 511];
}

__global__ void cast_bf16(const float* __restrict__ src, unsigned short* __restrict__ dst, int n4) {
  int i = blockIdx.x * 256 + threadIdx.x;
  if (i < n4) {
    float4 v = ((const float4*)src)[i];
    uint2 o;
    o.x = (unsigned int)f2bf(v.x) | ((unsigned int)f2bf(v.y) << 16);
    o.y = (unsigned int)f2bf(v.z) | ((unsigned int)f2bf(v.w) << 16);
    ((uint2*)dst)[i] = o;
  }
}

__global__ void seg_bounds(const int* __restrict__ seg, int* __restrict__ ss,
                           int* __restrict__ se, int T) {
  const int t = blockIdx.x * 256 + threadIdx.x;
  if (t >= T) return;
  const int sid = seg[t];
  int lo = 0, hi = T;
  while (lo < hi) { int mid = (lo + hi) >> 1; if (seg[mid] < sid) lo = mid + 1; else hi = mid; }
  ss[t] = lo;
  lo = t; hi = T;
  while (lo < hi) { int mid = (lo + hi) >> 1; if (seg[mid] <= sid) lo = mid + 1; else hi = mid; }
  se[t] = lo;
}

// ---------------------------------------------------------------------------
// bf16 MFMA GEMM: C[M,N] = A[M,K] * Bt[N,K]^T  (+bias, optional res/swish)
// MODE 0: out_bf16 = acc + bias
// MODE 1: out_f32  = res + acc + bias
// MODE 2: out_bf16 = swish(acc + bias)
// MF = m-fragments per wave; BM = MF*32 (128 or 64). BN = 128, BK = 64.
// Staging via global_load_lds (linear LDS dest, inverse-swizzled source so
// fragment reads use unit c ^ (row&7) — XOR involution both sides).
// ---------------------------------------------------------------------------
template <int MODE, int MF>
__launch_bounds__(256)
__global__ void gemm_bf16(const unsigned short* __restrict__ A,
                          const unsigned short* __restrict__ Bt,
                          int M, int N, int K,
                          const float* __restrict__ bias,
                          const float* __restrict__ res,
                          float* __restrict__ outF,
                          unsigned short* __restrict__ outB) {
  __shared__ uint4 As[MF * 256];  // BM rows x 8 x 16B
  __shared__ uint4 Bs[1024];      // 128 rows x 8 x 16B
  const int tid = threadIdx.x;
  const int lane = tid & 63;
  const int wv = tid >> 6;
  const int wm = wv >> 1, wn = wv & 1;
  const int l15 = lane & 15, l4 = lane >> 4;
  const int bm0 = blockIdx.x * (MF * 32);
  const int bn0 = blockIdx.y * 128;

  f32x4 acc[MF][4];
#pragma unroll
  for (int m = 0; m < MF; ++m)
#pragma unroll
    for (int n = 0; n < 4; ++n) acc[m][n] = (f32x4){0.f, 0.f, 0.f, 0.f};

  for (int k0 = 0; k0 < K; k0 += 64) {
#pragma unroll
    for (int i = 0; i < MF; ++i) {
      const int u = tid + i * 256;
      const int r = u >> 3;
      const int c = (u & 7) ^ (r & 7);
      GLOAD_LDS16(A + (size_t)(bm0 + r) * K + k0 + c * 8, &As[i * 256 + wv * 64]);
    }
#pragma unroll
    for (int i = 0; i < 4; ++i) {
      const int u = tid + i * 256;
      const int r = u >> 3;
      const int c = (u & 7) ^ (r & 7);
      GLOAD_LDS16(Bt + (size_t)(bn0 + r) * K + k0 + c * 8, &Bs[i * 256 + wv * 64]);
    }
    __syncthreads();
#pragma unroll
    for (int kk = 0; kk < 2; ++kk) {
      bf16x8 af[MF], bfr[4];
#pragma unroll
      for (int m = 0; m < MF; ++m) {
        const int row = wm * (MF * 16) + m * 16 + l15;
        const int c = kk * 4 + l4;
        af[m] = *(const bf16x8*)&As[row * 8 + (c ^ (row & 7))];
      }
#pragma unroll
      for (int n = 0; n < 4; ++n) {
        const int row = wn * 64 + n * 16 + l15;
        const int c = kk * 4 + l4;
        bfr[n] = *(const bf16x8*)&Bs[row * 8 + (c ^ (row & 7))];
      }
#pragma unroll
      for (int m = 0; m < MF; ++m)
#pragma unroll
        for (int n = 0; n < 4; ++n)
          acc[m][n] = __builtin_amdgcn_mfma_f32_16x16x32_bf16(af[m], bfr[n], acc[m][n], 0, 0, 0);
    }
    __syncthreads();
  }

  float bvals[4];
#pragma unroll
  for (int n = 0; n < 4; ++n) bvals[n] = bias[bn0 + wn * 64 + n * 16 + l15];

#pragma unroll
  for (int m = 0; m < MF; ++m) {
#pragma unroll
    for (int r = 0; r < 4; ++r) {
      const int R = bm0 + wm * (MF * 16) + m * 16 + l4 * 4 + r;
#pragma unroll
      for (int n = 0; n < 4; ++n) {
        const int C = bn0 + wn * 64 + n * 16 + l15;
        float v = acc[m][n][r] + bvals[n];
        if (MODE == 1) {
          v += res[(size_t)R * N + C];
          outF[(size_t)R * N + C] = v;
        } else if (MODE == 2) {
          v = v / (1.f + __expf(-v));
          outB[(size_t)R * N + C] = f2bf(v);
        } else {
          outB[(size_t)R * N + C] = f2bf(v);
        }
      }
    }
  }
}

// ---------------------------------------------------------------------------
// Segment-local flash attention, MFMA, ONE WAVE PER BLOCK (zero barriers).
// Flat grid 2048: head = bid & 7 (-> one head per XCD under round-robin
// dispatch: per-XCD K/V working set = 1MB, L2-resident), q0 = (bid>>3)*16.
// Single V LDS buffer (prefetch is in registers; per-wave DS ops are
// in-order, so no WAR hazard) -> 10.9KB LDS -> ~14 blocks/CU.
// Defer-max (THR=8): skip shuffle-max+rescale unless some lane exceeds.
// ---------------------------------------------------------------------------
__launch_bounds__(64)
__global__ void attn_mfma(const unsigned short* __restrict__ qkvcb,
                          const int* __restrict__ sstart,
                          const int* __restrict__ send,
                          unsigned short* __restrict__ aob) {
  __shared__ unsigned short Vt[64 * 68];  // [d][token]
  __shared__ unsigned short Pl[16 * 68];  // [row][key]
  const int lane = threadIdx.x;
  const int l15 = lane & 15;
  const int g = lane >> 4;
  const int head = blockIdx.x & 7;
  const int q0 = (blockIdx.x >> 3) * 16;

  // Q A-fragments (row = l15, k-slice = g*8..+7 per 32-k step)
  const size_t qbase = (size_t)(q0 + l15) * 2048 + head * 64;
  const bf16x8 qf0 = *(const bf16x8*)(qkvcb + qbase + g * 8);
  const bf16x8 qf1 = *(const bf16x8*)(qkvcb + qbase + 32 + g * 8);

  int sr[4], er[4];
#pragma unroll
  for (int r = 0; r < 4; ++r) {
    const int q = q0 + 4 * g + r;
    sr[r] = sstart[q];
    er[r] = send[q];
  }
  const int s0 = sstart[q0];
  const int e1 = send[q0 + 15];

  // staged V rows (lane = token) and K fragments, reused across tiles
  uint4 vreg[8];
  bf16x8 kfa[4], kfb[4];

  auto LOADV = [&](int k0) {
    const unsigned short* vrow =
        qkvcb + (size_t)min(k0 + lane, TTOK - 1) * 2048 + 1024 + head * 64;
#pragma unroll
    for (int d8 = 0; d8 < 8; ++d8) vreg[d8] = *(const uint4*)(vrow + d8 * 8);
  };
  auto LOADK = [&](int k0) {
#pragma unroll
    for (int n = 0; n < 4; ++n) {
      const size_t kb =
          (size_t)min(k0 + 16 * n + l15, TTOK - 1) * 2048 + 512 + head * 64;
      kfa[n] = *(const bf16x8*)(qkvcb + kb + g * 8);
      kfb[n] = *(const bf16x8*)(qkvcb + kb + 32 + g * 8);
    }
  };
  LOADV(s0);
  LOADK(s0);

  float m_[4], l_[4];
  f32x4 o[4];
#pragma unroll
  for (int r = 0; r < 4; ++r) { m_[r] = -1e30f; l_[r] = 0.f; }
#pragma unroll
  for (int n = 0; n < 4; ++n) o[n] = (f32x4){0.f, 0.f, 0.f, 0.f};

  for (int k0 = s0; k0 < e1; k0 += 64) {
    // ---- (a) staged V regs -> Vt (transpose; conflict-free writes) ----
#pragma unroll
    for (int d8 = 0; d8 < 8; ++d8) {
      const unsigned int uu[4] = {vreg[d8].x, vreg[d8].y, vreg[d8].z, vreg[d8].w};
#pragma unroll
      for (int t2 = 0; t2 < 4; ++t2) {
        Vt[(d8 * 8 + 2 * t2) * 68 + lane] = (unsigned short)(uu[t2] & 0xFFFFu);
        Vt[(d8 * 8 + 2 * t2 + 1) * 68 + lane] = (unsigned short)(uu[t2] >> 16);
      }
    }

    // ---- (b) S = Q K^T (consume prefetched K frags) ----
    f32x4 sac[4];
#pragma unroll
    for (int n = 0; n < 4; ++n) {
      f32x4 z = (f32x4){0.f, 0.f, 0.f, 0.f};
      z = __builtin_amdgcn_mfma_f32_16x16x32_bf16(qf0, kfa[n], z, 0, 0, 0);
      sac[n] = __builtin_amdgcn_mfma_f32_16x16x32_bf16(qf1, kfb[n], z, 0, 0, 0);
    }

    // ---- (c) issue next tile's loads (regs free after (a)/(b)) ----
    const int k0n = (k0 + 64 < e1) ? (k0 + 64) : s0;
    LOADV(k0n);
    LOADK(k0n);

    // ---- (d) scale + segment mask + online softmax (defer-max) ----
    float pv[4][4];  // [n][reg]
    float pmax[4] = {-1e30f, -1e30f, -1e30f, -1e30f};
#pragma unroll
    for (int n = 0; n < 4; ++n) {
      const int col = k0 + 16 * n + l15;
#pragma unroll
      for (int r = 0; r < 4; ++r) {
        float v = sac[n][r] * 0.125f;
        if (col < sr[r] || col >= er[r]) v = -1e30f;
        pv[n][r] = v;
        pmax[r] = fmaxf(pmax[r], v);
      }
    }
    bool need = false;
#pragma unroll
    for (int r = 0; r < 4; ++r) need |= (pmax[r] > m_[r] + 8.f);
    if (__any(need)) {
      float tm[4];
#pragma unroll
      for (int r = 0; r < 4; ++r) tm[r] = pmax[r];
#pragma unroll
      for (int off = 1; off < 16; off <<= 1) {
#pragma unroll
        for (int r = 0; r < 4; ++r) tm[r] = fmaxf(tm[r], __shfl_xor(tm[r], off));
      }
      f32x4 corrv;
#pragma unroll
      for (int r = 0; r < 4; ++r) {
        const float nm = fmaxf(m_[r], tm[r]);
        const float corr = __expf(m_[r] - nm);
        m_[r] = nm;
        l_[r] *= corr;
        corrv[r] = corr;
      }
#pragma unroll
      for (int n = 0; n < 4; ++n) o[n] *= corrv;
    }
    float psum[4] = {0.f, 0.f, 0.f, 0.f};
#pragma unroll
    for (int n = 0; n < 4; ++n) {
#pragma unroll
      for (int r = 0; r < 4; ++r) {
        const float p = __expf(pv[n][r] - m_[r]);
        pv[n][r] = p;
        psum[r] += p;
      }
    }
#pragma unroll
    for (int off = 1; off < 16; off <<= 1) {
#pragma unroll
      for (int r = 0; r < 4; ++r) psum[r] += __shfl_xor(psum[r], off);
    }
#pragma unroll
    for (int r = 0; r < 4; ++r) l_[r] += psum[r];

    // ---- (e) P -> LDS, read A-frags, PV from Vt ----
#pragma unroll
    for (int n = 0; n < 4; ++n)
#pragma unroll
      for (int r = 0; r < 4; ++r)
        Pl[(4 * g + r) * 68 + 16 * n + l15] = f2bf(pv[n][r]);

    const bf16x8 pa0 = *(const bf16x8*)(Pl + l15 * 68 + g * 8);
    const bf16x8 pa1 = *(const bf16x8*)(Pl + l15 * 68 + 32 + g * 8);
#pragma unroll
    for (int n = 0; n < 4; ++n) {
      const bf16x8 vb0 = *(const bf16x8*)(Vt + (16 * n + l15) * 68 + g * 8);
      const bf16x8 vb1 = *(const bf16x8*)(Vt + (16 * n + l15) * 68 + 32 + g * 8);
      o[n] = __builtin_amdgcn_mfma_f32_16x16x32_bf16(pa0, vb0, o[n], 0, 0, 0);
      o[n] = __builtin_amdgcn_mfma_f32_16x16x32_bf16(pa1, vb1, o[n], 0, 0, 0);
    }
  }

  // ---- normalize, add c, store ----
  float rl[4];
#pragma unroll
  for (int r = 0; r < 4; ++r) rl[r] = 1.f / l_[r];
#pragma unroll
  for (int n = 0; n < 4; ++n) {
#pragma unroll
    for (int r = 0; r < 4; ++r) {
      const int q = q0 + 4 * g + r;
      const int d = head * 64 + 16 * n + l15;
      const float cv = bf2f(qkvcb[(size_t)q * 2048 + 1536 + d]);
      aob[(size_t)q * 512 + d] = f2bf(o[n][r] * rl[r] + cv);
    }
  }
}

// ---------------------------------------------------------------------------
// TF-style LayerNorm over D=512: out = g*(x-u)/sqrt(var+1e-12)+b
// ---------------------------------------------------------------------------
__launch_bounds__(64)
__global__ void ln_kernel(const float* __restrict__ x, const float* __restrict__ g,
                          const float* __restrict__ b, float* __restrict__ outF,
                          unsigned short* __restrict__ outB) {
  const int row = blockIdx.x;
  const int lane = threadIdx.x;
  const float4* xr = (const float4*)(x + (size_t)row * 512);
  float4 a = xr[lane * 2], c = xr[lane * 2 + 1];
  float s = a.x + a.y + a.z + a.w + c.x + c.y + c.z + c.w;
  float sq = a.x * a.x + a.y * a.y + a.z * a.z + a.w * a.w +
             c.x * c.x + c.y * c.y + c.z * c.z + c.w * c.w;
#pragma unroll
  for (int off = 1; off < 64; off <<= 1) {
    s += __shfl_xor(s, off);
    sq += __shfl_xor(sq, off);
  }
  const float mean = s * (1.f / 512.f);
  const float var = sq * (1.f / 512.f) - mean * mean;
  const float rstd = rsqrtf(var + 1e-12f);
  const float4* gr = (const float4*)g;
  const float4* br = (const float4*)b;
  float4 g0 = gr[lane * 2], g1v = gr[lane * 2 + 1];
  float4 b0 = br[lane * 2], b1v = br[lane * 2 + 1];
  float4 y0, y1;
  y0.x = (a.x - mean) * rstd * g0.x + b0.x;
  y0.y = (a.y - mean) * rstd * g0.y + b0.y;
  y0.z = (a.z - mean) * rstd * g0.z + b0.z;
  y0.w = (a.w - mean) * rstd * g0.w + b0.w;
  y1.x = (c.x - mean) * rstd * g1v.x + b1v.x;
  y1.y = (c.y - mean) * rstd * g1v.y + b1v.y;
  y1.z = (c.z - mean) * rstd * g1v.z + b1v.z;
  y1.w = (c.w - mean) * rstd * g1v.w + b1v.w;
  float4* of = (float4*)(outF + (size_t)row * 512);
  of[lane * 2] = y0;
  of[lane * 2 + 1] = y1;
  uint4 ob;
  ob.x = (unsigned int)f2bf(y0.x) | ((unsigned int)f2bf(y0.y) << 16);
  ob.y = (unsigned int)f2bf(y0.z) | ((unsigned int)f2bf(y0.w) << 16);
  ob.z = (unsigned int)f2bf(y1.x) | ((unsigned int)f2bf(y1.y) << 16);
  ob.w = (unsigned int)f2bf(y1.z) | ((unsigned int)f2bf(y1.w) << 16);
  ((uint4*)(outB + (size_t)row * 512))[lane] = ob;
}

// ---------------------------------------------------------------------------
extern "C" void kernel_launch(void* const* d_in, const int* in_sizes, int n_in,
                              void* d_out, int out_size, void* d_ws, size_t ws_size,
                              hipStream_t stream) {
  const float* h_in = (const float*)d_in[0];
  const int* seg = (const int*)d_in[1];
  const float* Wq = (const float*)d_in[2];
  const float* bq = (const float*)d_in[3];
  const float* Wk = (const float*)d_in[4];
  const float* bk = (const float*)d_in[5];
  const float* Wv = (const float*)d_in[6];
  const float* bv = (const float*)d_in[7];
  const float* Wc = (const float*)d_in[8];
  const float* bc = (const float*)d_in[9];
  const float* Wp = (const float*)d_in[10];
  const float* bp = (const float*)d_in[11];
  const float* g1 = (const float*)d_in[12];
  const float* b1 = (const float*)d_in[13];
  const float* g2 = (const float*)d_in[14];
  const float* b2 = (const float*)d_in[15];
  const float* W1 = (const float*)d_in[16];
  const float* fb1 = (const float*)d_in[17];
  const float* W2 = (const float*)d_in[18];
  const float* fb2 = (const float*)d_in[19];
  float* outp = (float*)d_out;

  char* p = (char*)d_ws;
  auto alloc = [&](size_t bytes) {
    char* r = p;
    p += (bytes + 255) & ~(size_t)255;
    return r;
  };
  unsigned short* wqkvcb = (unsigned short*)alloc((size_t)2048 * 512 * 2);
  unsigned short* wpb = (unsigned short*)alloc((size_t)512 * 512 * 2);
  unsigned short* w1b = (unsigned short*)alloc((size_t)2048 * 512 * 2);
  unsigned short* w2b = (unsigned short*)alloc((size_t)512 * 2048 * 2);
  float* bqkvc = (float*)alloc(2048 * 4);
  unsigned short* hb = (unsigned short*)alloc((size_t)TTOK * 512 * 2);
  unsigned short* qkvcb = (unsigned short*)alloc((size_t)TTOK * 2048 * 2);
  unsigned short* aob = (unsigned short*)alloc((size_t)TTOK * 512 * 2);
  float* xbuf = (float*)alloc((size_t)TTOK * 512 * 4);
  float* h1 = (float*)alloc((size_t)TTOK * 512 * 4);
  unsigned short* h1b = (unsigned short*)alloc((size_t)TTOK * 512 * 2);
  unsigned short* f1b = (unsigned short*)alloc((size_t)TTOK * 2048 * 2);
  float* hcur = (float*)alloc((size_t)TTOK * 512 * 4);
  int* sstart = (int*)alloc(TTOK * 4);
  int* send = (int*)alloc(TTOK * 4);

  dim3 tb(32, 8);
  transpose_cast<<<dim3(16, 16), tb, 0, stream>>>(Wq, wqkvcb + 0 * 512 * 512, 512, 512);
  transpose_cast<<<dim3(16, 16), tb, 0, stream>>>(Wk, wqkvcb + 1 * 512 * 512, 512, 512);
  transpose_cast<<<dim3(16, 16), tb, 0, stream>>>(Wv, wqkvcb + 2 * 512 * 512, 512, 512);
  transpose_cast<<<dim3(16, 16), tb, 0, stream>>>(Wc, wqkvcb + 3 * 512 * 512, 512, 512);
  transpose_cast<<<dim3(16, 16), tb, 0, stream>>>(Wp, wpb, 512, 512);
  transpose_cast<<<dim3(64, 16), tb, 0, stream>>>(W1, w1b, 512, 2048);
  transpose_cast<<<dim3(16, 64), tb, 0, stream>>>(W2, w2b, 2048, 512);
  pack_bias<<<8, 256, 0, stream>>>(bq, bk, bv, bc, bqkvc);
  cast_bf16<<<2048, 256, 0, stream>>>(h_in, hb, TTOK * 512 / 4);
  seg_bounds<<<16, 256, 0, stream>>>(seg, sstart, send, TTOK);

  const float* resp = h_in;
  for (int layer = 0; layer < NLAYER; ++layer) {
    // QKVC projection: [4096,512] x [512,2048]
    gemm_bf16<0, 4><<<dim3(32, 16), 256, 0, stream>>>(hb, wqkvcb, TTOK, 2048, 512,
                                                      bqkvc, nullptr, nullptr, qkvcb);
    // segment-local MFMA flash attention (+c), bf16 out
    attn_mfma<<<dim3(2048), 64, 0, stream>>>(qkvcb, sstart, send, aob);
    // attn_out @ Wp + bp + prev  -> xbuf (f32)
    gemm_bf16<1, 2><<<dim3(64, 4), 256, 0, stream>>>(aob, wpb, TTOK, 512, 512,
                                                     bp, resp, xbuf, nullptr);
    ln_kernel<<<TTOK, 64, 0, stream>>>(xbuf, g1, b1, h1, h1b);
    // FFN1: swish(h1 @ W1 + fb1) -> f1b (bf16)
    gemm_bf16<2, 4><<<dim3(32, 16), 256, 0, stream>>>(h1b, w1b, TTOK, 2048, 512,
                                                      fb1, nullptr, nullptr, f1b);
    // FFN2: f1 @ W2 + fb2 + h1 -> xbuf (f32)
    gemm_bf16<1, 2><<<dim3(64, 4), 256, 0, stream>>>(f1b, w2b, TTOK, 512, 2048,
                                                     fb2, h1, xbuf, nullptr);
    float* lnout = (layer == NLAYER - 1) ? outp : hcur;
    ln_kernel<<<TTOK, 64, 0, stream>>>(xbuf, g2, b2, lnout, hb);
    resp = hcur;
  }
}